// Round 2
// baseline (13170.630 us; speedup 1.0000x reference)
//
#include <hip/hip_runtime.h>

// Problem constants (B,S,D=16,2048,256; K codebooks=8, CD=1024)
#define DD    256
#define KST   8
#define CDN   1024
#define NROWS 32768          // B*S
#define ROWS  32             // rows (tokens) per block
#define NT    512            // codeword tile per sweep (2 tiles per stage)
#define KC    2              // k-chunk staged in LDS (double-buffered)
#define NCH   (DD / KC)      // 128 chunks per jb tile
#define TCH   (2 * NCH)      // 256 chunks per stage
#define AST   32             // a_t row stride (bank-perfect for sumsq/update)
#define BST   256            // b tile col stride per 256-col half

__device__ __forceinline__ bool better(float a, int ja, float b, int jb_) {
    return (a < b) || (a == b && ja < jb_);
}

// ---------------------------------------------------------------------------
// numpy AVX512 pairwise sum-of-squares over 256 values (bit-emulated).
template <typename F>
__device__ __forceinline__ float np_sumsq_256(F ld) {
    float Sv = 0.f;
#pragma unroll
    for (int blk = 0; blk < 2; ++blk) {
        const int o = blk * 128;
        float w[16];
#pragma unroll
        for (int l = 0; l < 16; ++l) {
            float v[8];
#pragma unroll
            for (int j = 0; j < 8; ++j) {
                float xv = ld(o + 16 * j + l);
                v[j] = __fmul_rn(xv, xv);
            }
            float a01 = __fadd_rn(v[0], v[1]);
            float a23 = __fadd_rn(v[2], v[3]);
            float a45 = __fadd_rn(v[4], v[5]);
            float a67 = __fadd_rn(v[6], v[7]);
            w[l] = __fadd_rn(__fadd_rn(a01, a23), __fadd_rn(a45, a67));
        }
        float t8[8];
#pragma unroll
        for (int l = 0; l < 8; ++l) t8[l] = __fadd_rn(w[l], w[l + 8]);
        float t4[4];
#pragma unroll
        for (int l = 0; l < 4; ++l) t4[l] = __fadd_rn(t8[l], t8[l + 4]);
        float t2_0 = __fadd_rn(t4[0], t4[2]);
        float t2_1 = __fadd_rn(t4[1], t4[3]);
        float bs = __fadd_rn(t2_0, t2_1);
        Sv = (blk == 0) ? bs : __fadd_rn(Sv, bs);
    }
    return Sv;
}

// ---------------------------------------------------------------------------
__global__ __launch_bounds__(256) void norms_kernel(const float* __restrict__ cb,
                                                    float* __restrict__ n32) {
    int j = blockIdx.x * 256 + threadIdx.x;   // 0..8191
    const float* p = cb + (size_t)j * DD;
    n32[j] = np_sumsq_256([&](int i) { return p[i]; });
}

// ---------------------------------------------------------------------------
// Stage one codeword's 2 k-values (one float2) into the transposed B tile.
// j in 0..511 within tile; half h = j>>8, column jj = j&255.
// Store banks: jj consecutive across lanes -> 2-way only (free).
__device__ __forceinline__ void st_chunk2(float (*bb)[KC][BST], int j, float2 v) {
    int h = j >> 8, jj = j & 255;
    bb[h][0][jj] = v.x;
    bb[h][1][jj] = v.y;
}

// ---------------------------------------------------------------------------
// Fused RVQ — numpy-fp32 emulation, restructured for full residency:
//  * LDS = 40960 B exactly -> 4 blocks/CU -> ALL 1024 blocks resident, no
//    tail round (round 1 measured: per-block latency ~constant, tail round
//    did 25% of work in 43% of time).
//  * Prefetch issued AFTER the barrier (hipcc drains vmcnt(0) before every
//    s_barrier; the old order exposed full load latency at every barrier).
//  * rowS lives in registers (staged through the btb area once per stage);
//    rowidx/wred overlay btb; indices written directly to global per stage.
// Per-(row,col) dot chain stays single-accumulator FMA with k ascending ->
// scores bit-identical to the previous passing kernel.
__global__ __launch_bounds__(256, 4) void rvq_kernel(const float* __restrict__ x,
                                                     const float* __restrict__ cbs,
                                                     const float* __restrict__ n32,
                                                     float* __restrict__ out) {
    __shared__ __align__(16) float a_t[DD][AST];       // 32768 B residual^T
    __shared__ __align__(16) float btb[2][2][KC][BST]; // 8192 B dbuf B tile
    float* sc  = &btb[0][0][0][0];   // overlay: rowS / rowidx / wred
    int*   sci = (int*)sc;

    const int tid  = threadIdx.x;
    const int base = blockIdx.x * ROWS;
    const int tx   = tid & 63;            // col-group: cols {h*256 + tx*4 + c}
    const int ty   = tid >> 6;            // wave id = row-group (8 rows)
    const int row0 = ty * 8;
    const int urow = tid & 31;            // update row
    const int ug   = tid >> 5;            // owned 32-dim segment

    for (int i = tid; i < ROWS * DD / 4; i += 256) {
        int row = i >> 6;
        int dq  = i & 63;
        float4 v = ((const float4*)(x + (size_t)(base + row) * DD))[dq];
        int d = dq * 4;
        a_t[d + 0][row] = v.x; a_t[d + 1][row] = v.y;
        a_t[d + 2][row] = v.z; a_t[d + 3][row] = v.w;
    }

    float loss_acc = 0.f;
    const int j0 = tid, j1 = tid + 256;   // codeword slots this thread stages

    for (int s = 0; s < KST; ++s) {
        const float* cb = cbs + (size_t)s * CDN * DD;
        const float* nr = n32 + s * CDN;
        __syncthreads();                  // (A) a_t ready; prev-stage sci reads done

        // np-AVX512 S = sum(res*res) per row; staged via btb overlay -> regs
        if (tid < ROWS) {
            int row = tid;
            sc[row] = np_sumsq_256([&](int i) { return a_t[i][row]; });
        }
        __syncthreads();                  // (B) rowS visible
        float Srow[8];
#pragma unroll
        for (int r = 0; r < 8; ++r) Srow[r] = sc[row0 + r];
        __syncthreads();                  // (C) rowS consumed; btb free

        float rb[8]; int rjx[8];
#pragma unroll
        for (int r = 0; r < 8; ++r) { rb[r] = 3.4e38f; rjx[r] = 0x7ffffff; }
        float acc[8][8];

        // prestore chunk 0 into buffer 0
        {
            float2 p0 = *(const float2*)(cb + (size_t)j0 * DD);
            float2 p1 = *(const float2*)(cb + (size_t)j1 * DD);
            st_chunk2(btb[0], j0, p0);
            st_chunk2(btb[0], j1, p1);
        }

#pragma unroll 2
        for (int t = 0; t < TCH; ++t) {
            const int buf = t & 1;
            __syncthreads();              // btb[buf] ready (stores from t-1)

            float2 nx0, nx1;
            const bool pf = (t + 1 < TCH);
            if (pf) {                     // prefetch AFTER barrier: latency
                int jb2 = ((t + 1) >> 7) * NT, kk2 = ((t + 1) & 127) * KC;
                nx0 = *(const float2*)(cb + (size_t)(jb2 + j0) * DD + kk2);
                nx1 = *(const float2*)(cb + (size_t)(jb2 + j1) * DD + kk2);
            }

            const int jb = (t >> 7) * NT, kk = (t & 127) * KC;
            if ((t & 127) == 0) {
#pragma unroll
                for (int r = 0; r < 8; ++r)
#pragma unroll
                    for (int c = 0; c < 8; ++c) acc[r][c] = 0.f;
            }
            const float (*b0p)[BST] = btb[buf][0];
            const float (*b1p)[BST] = btb[buf][1];
#pragma unroll
            for (int k = 0; k < KC; ++k) {
                // A: wave-uniform 16B reads (all 64 lanes same address)
                float4 a0 = *(const float4*)&a_t[kk + k][row0];
                float4 a1 = *(const float4*)&a_t[kk + k][row0 + 4];
                // B: lanes 0..63 read contiguous 1KB -> conflict-free b128
                float4 b0 = *(const float4*)&b0p[k][tx * 4];
                float4 b1 = *(const float4*)&b1p[k][tx * 4];
                float av[8] = {a0.x, a0.y, a0.z, a0.w, a1.x, a1.y, a1.z, a1.w};
                float bw[8] = {b0.x, b0.y, b0.z, b0.w, b1.x, b1.y, b1.z, b1.w};
#pragma unroll
                for (int r = 0; r < 8; ++r)
#pragma unroll
                    for (int c = 0; c < 8; ++c)
                        acc[r][c] = __builtin_fmaf(av[r], bw[c], acc[r][c]);
            }
            if (pf) {                     // stage prefetched chunk (covers latency)
                st_chunk2(btb[buf ^ 1], j0, nx0);
                st_chunk2(btb[buf ^ 1], j1, nx1);
            }
            if ((t & 127) == 127) {       // np-composed score + argmin for this jb
                float nrv[2][4];
#pragma unroll
                for (int h = 0; h < 2; ++h)
#pragma unroll
                    for (int c = 0; c < 4; ++c)
                        nrv[h][c] = nr[jb + h * 256 + tx * 4 + c];
#pragma unroll
                for (int r = 0; r < 8; ++r) {
                    float t1 = 3.4e38f; int u1 = 0x7ffffff;
#pragma unroll
                    for (int h = 0; h < 2; ++h)
#pragma unroll
                        for (int c = 0; c < 4; ++c) {
                            int j = jb + h * 256 + tx * 4 + c;
                            float m2 = __fmul_rn(2.f, acc[r][h * 4 + c]);
                            float sc2 = __fadd_rn(__fsub_rn(Srow[r], m2), nrv[h][c]);
                            if (better(sc2, j, t1, u1)) { t1 = sc2; u1 = j; }
                        }
#pragma unroll
                    for (int off = 32; off >= 1; off >>= 1) {
                        float ob = __shfl_xor(t1, off, 64);
                        int   oj = __shfl_xor(u1, off, 64);
                        if (better(ob, oj, t1, u1)) { t1 = ob; u1 = oj; }
                    }
                    if (tx == 0 && better(t1, u1, rb[r], rjx[r])) { rb[r] = t1; rjx[r] = u1; }
                }
            }
        }
        // publish chosen indices: LDS overlay (disjoint from btb[1], which the
        // last chunk read) + direct global write of the index output
        if (tx == 0) {
#pragma unroll
            for (int r = 0; r < 8; ++r) {
                sci[row0 + r] = rjx[r];
                out[2 + (size_t)(base + row0 + r) * KST + s] = (float)rjx[r];
            }
        }
        __syncthreads();                  // (D) rowidx visible

        // residual update + loss (elementwise fp32; banks 2-way via remap)
        {
            int bi = sci[urow];
            const float4* cp = (const float4*)(cb + (size_t)bi * DD + ug * 32);
#pragma unroll
            for (int dq = 0; dq < 8; ++dq) {
                float4 v = cp[dq];
                int d = ug * 32 + dq * 4;
                float e0 = __fsub_rn(a_t[d + 0][urow], v.x); a_t[d + 0][urow] = e0;
                float e1 = __fsub_rn(a_t[d + 1][urow], v.y); a_t[d + 1][urow] = e1;
                float e2 = __fsub_rn(a_t[d + 2][urow], v.z); a_t[d + 2][urow] = e2;
                float e3 = __fsub_rn(a_t[d + 3][urow], v.w); a_t[d + 3][urow] = e3;
                loss_acc += e0 * e0 + e1 * e1 + e2 * e2 + e3 * e3;
            }
        }
    }
    __syncthreads();                      // (E) a_t final; sci reads done

    // ---- outputs ---- (indices already written per stage)
    float* q = out + 2 + (size_t)NROWS * KST;
    for (int i = tid; i < ROWS * DD / 4; i += 256) {
        int row = i >> 6, dq = i & 63, d = dq * 4;
        float4 xv = ((const float4*)(x + (size_t)(base + row) * DD))[dq];
        float4 o;
        o.x = xv.x - a_t[d + 0][row];
        o.y = xv.y - a_t[d + 1][row];
        o.z = xv.z - a_t[d + 2][row];
        o.w = xv.w - a_t[d + 3][row];
        ((float4*)(q + (size_t)(base + row) * DD))[dq] = o;
    }
#pragma unroll
    for (int off = 32; off >= 1; off >>= 1) loss_acc += __shfl_down(loss_acc, off, 64);
    if ((tid & 63) == 0) sc[tid >> 6] = loss_acc;   // wred overlay
    __syncthreads();
    if (tid == 0) {
        float t = sc[0] + sc[1] + sc[2] + sc[3];
        t *= (1.f / ((float)NROWS * (float)DD));
        atomicAdd(out + 0, t);
        atomicAdd(out + 1, t);
    }
}

// ---------------------------------------------------------------------------
extern "C" void kernel_launch(void* const* d_in, const int* in_sizes, int n_in,
                              void* d_out, int out_size, void* d_ws, size_t ws_size,
                              hipStream_t stream) {
    const float* x   = (const float*)d_in[0];   // [16,2048,256] fp32
    const float* cbs = (const float*)d_in[1];   // [8,1024,256] fp32
    float* out = (float*)d_out;
    float* n32 = (float*)d_ws;                  // 8192 floats

    hipMemsetAsync(d_out, 0, 2 * sizeof(float), stream);
    norms_kernel<<<32, 256, 0, stream>>>(cbs, n32);
    rvq_kernel<<<NROWS / ROWS, 256, 0, stream>>>(x, cbs, n32, out);
}

// Round 3
// 5641.249 us; speedup vs baseline: 2.3347x; 2.3347x over previous
//
#include <hip/hip_runtime.h>

// Problem constants (B,S,D=16,2048,256; K codebooks=8, CD=1024)
#define DD    256
#define KST   8
#define CDN   1024
#define NROWS 32768          // B*S
#define ROWS  32             // rows (tokens) per block
#define NT    512            // codeword tile per sweep (2 tiles per stage)
#define KC    2              // k-chunk staged in LDS (double-buffered)
#define NCH   (DD / KC)      // 128 chunks per jb tile
#define TCH   (2 * NCH)      // 256 chunks per stage
#define AST   32             // a_t row stride (bank-perfect for sumsq/update)
#define BST   256            // b tile col stride per 256-col half

__device__ __forceinline__ bool better(float a, int ja, float b, int jb_) {
    return (a < b) || (a == b && ja < jb_);
}

// ---------------------------------------------------------------------------
// numpy AVX512 pairwise sum-of-squares over 256 values (bit-emulated).
template <typename F>
__device__ __forceinline__ float np_sumsq_256(F ld) {
    float Sv = 0.f;
#pragma unroll
    for (int blk = 0; blk < 2; ++blk) {
        const int o = blk * 128;
        float w[16];
#pragma unroll
        for (int l = 0; l < 16; ++l) {
            float v[8];
#pragma unroll
            for (int j = 0; j < 8; ++j) {
                float xv = ld(o + 16 * j + l);
                v[j] = __fmul_rn(xv, xv);
            }
            float a01 = __fadd_rn(v[0], v[1]);
            float a23 = __fadd_rn(v[2], v[3]);
            float a45 = __fadd_rn(v[4], v[5]);
            float a67 = __fadd_rn(v[6], v[7]);
            w[l] = __fadd_rn(__fadd_rn(a01, a23), __fadd_rn(a45, a67));
        }
        float t8[8];
#pragma unroll
        for (int l = 0; l < 8; ++l) t8[l] = __fadd_rn(w[l], w[l + 8]);
        float t4[4];
#pragma unroll
        for (int l = 0; l < 4; ++l) t4[l] = __fadd_rn(t8[l], t8[l + 4]);
        float t2_0 = __fadd_rn(t4[0], t4[2]);
        float t2_1 = __fadd_rn(t4[1], t4[3]);
        float bs = __fadd_rn(t2_0, t2_1);
        Sv = (blk == 0) ? bs : __fadd_rn(Sv, bs);
    }
    return Sv;
}

// ---------------------------------------------------------------------------
__global__ __launch_bounds__(256) void norms_kernel(const float* __restrict__ cb,
                                                    float* __restrict__ n32) {
    int j = blockIdx.x * 256 + threadIdx.x;   // 0..8191
    const float* p = cb + (size_t)j * DD;
    n32[j] = np_sumsq_256([&](int i) { return p[i]; });
}

// ---------------------------------------------------------------------------
// Stage one codeword's 2 k-values (one float2) into the transposed B tile.
// j in 0..511 within tile; half h = j>>8, column jj = j&255.
// Store banks: jj consecutive across lanes -> 2-way only (free).
__device__ __forceinline__ void st_chunk2(float (*bb)[KC][BST], int j, float2 v) {
    int h = j >> 8, jj = j & 255;
    bb[h][0][jj] = v.x;
    bb[h][1][jj] = v.y;
}

// ---------------------------------------------------------------------------
// Fused RVQ — numpy-fp32 emulation, full-residency structure:
//  * LDS = 40960 B exactly -> 4 blocks/CU -> ALL 1024 blocks resident, no
//    tail round.
//  * Prefetch issued AFTER the barrier (hipcc drains vmcnt(0) before every
//    s_barrier; issuing before exposed full load latency at every barrier).
//  * rowS staged through the btb overlay into registers; rowidx/wred overlay
//    btb; indices written directly to global per stage.
//  * __launch_bounds__(256, 3): round 2 showed (256,4) clamps the allocator
//    to 64 VGPRs and spills acc[8][8] to scratch (45 GB/dispatch of HBM
//    traffic). At <=128 VGPRs the HW still gives 4 waves/SIMD = 4 blocks/CU
//    (m69 occupancy rule), so the bound stays at 3 and residency comes from
//    LDS+VGPR fitting 4x.
// Per-(row,col) dot chain stays single-accumulator FMA with k ascending ->
// scores bit-identical to the previous passing kernel.
__global__ __launch_bounds__(256, 3) void rvq_kernel(const float* __restrict__ x,
                                                     const float* __restrict__ cbs,
                                                     const float* __restrict__ n32,
                                                     float* __restrict__ out) {
    __shared__ __align__(16) float a_t[DD][AST];       // 32768 B residual^T
    __shared__ __align__(16) float btb[2][2][KC][BST]; // 8192 B dbuf B tile
    float* sc  = &btb[0][0][0][0];   // overlay: rowS / rowidx / wred
    int*   sci = (int*)sc;

    const int tid  = threadIdx.x;
    const int base = blockIdx.x * ROWS;
    const int tx   = tid & 63;            // col-group: cols {h*256 + tx*4 + c}
    const int ty   = tid >> 6;            // wave id = row-group (8 rows)
    const int row0 = ty * 8;
    const int urow = tid & 31;            // update row
    const int ug   = tid >> 5;            // owned 32-dim segment

    for (int i = tid; i < ROWS * DD / 4; i += 256) {
        int row = i >> 6;
        int dq  = i & 63;
        float4 v = ((const float4*)(x + (size_t)(base + row) * DD))[dq];
        int d = dq * 4;
        a_t[d + 0][row] = v.x; a_t[d + 1][row] = v.y;
        a_t[d + 2][row] = v.z; a_t[d + 3][row] = v.w;
    }

    float loss_acc = 0.f;
    const int j0 = tid, j1 = tid + 256;   // codeword slots this thread stages

    for (int s = 0; s < KST; ++s) {
        const float* cb = cbs + (size_t)s * CDN * DD;
        const float* nr = n32 + s * CDN;
        __syncthreads();                  // (A) a_t ready; prev-stage sci reads done

        // np-AVX512 S = sum(res*res) per row; staged via btb overlay -> regs
        if (tid < ROWS) {
            int row = tid;
            sc[row] = np_sumsq_256([&](int i) { return a_t[i][row]; });
        }
        __syncthreads();                  // (B) rowS visible
        float Srow[8];
#pragma unroll
        for (int r = 0; r < 8; ++r) Srow[r] = sc[row0 + r];
        __syncthreads();                  // (C) rowS consumed; btb free

        float rb[8]; int rjx[8];
#pragma unroll
        for (int r = 0; r < 8; ++r) { rb[r] = 3.4e38f; rjx[r] = 0x7ffffff; }
        float acc[8][8];

        // prestore chunk 0 into buffer 0
        {
            float2 p0 = *(const float2*)(cb + (size_t)j0 * DD);
            float2 p1 = *(const float2*)(cb + (size_t)j1 * DD);
            st_chunk2(btb[0], j0, p0);
            st_chunk2(btb[0], j1, p1);
        }

#pragma unroll 2
        for (int t = 0; t < TCH; ++t) {
            const int buf = t & 1;
            __syncthreads();              // btb[buf] ready (stores from t-1)

            float2 nx0, nx1;
            const bool pf = (t + 1 < TCH);
            if (pf) {                     // prefetch AFTER barrier: latency
                int jb2 = ((t + 1) >> 7) * NT, kk2 = ((t + 1) & 127) * KC;
                nx0 = *(const float2*)(cb + (size_t)(jb2 + j0) * DD + kk2);
                nx1 = *(const float2*)(cb + (size_t)(jb2 + j1) * DD + kk2);
            }

            const int jb = (t >> 7) * NT, kk = (t & 127) * KC;
            if ((t & 127) == 0) {
#pragma unroll
                for (int r = 0; r < 8; ++r)
#pragma unroll
                    for (int c = 0; c < 8; ++c) acc[r][c] = 0.f;
            }
            const float (*b0p)[BST] = btb[buf][0];
            const float (*b1p)[BST] = btb[buf][1];
#pragma unroll
            for (int k = 0; k < KC; ++k) {
                // A: wave-uniform 16B reads (all 64 lanes same address)
                float4 a0 = *(const float4*)&a_t[kk + k][row0];
                float4 a1 = *(const float4*)&a_t[kk + k][row0 + 4];
                // B: lanes 0..63 read contiguous 1KB -> conflict-free b128
                float4 b0 = *(const float4*)&b0p[k][tx * 4];
                float4 b1 = *(const float4*)&b1p[k][tx * 4];
                float av[8] = {a0.x, a0.y, a0.z, a0.w, a1.x, a1.y, a1.z, a1.w};
                float bw[8] = {b0.x, b0.y, b0.z, b0.w, b1.x, b1.y, b1.z, b1.w};
#pragma unroll
                for (int r = 0; r < 8; ++r)
#pragma unroll
                    for (int c = 0; c < 8; ++c)
                        acc[r][c] = __builtin_fmaf(av[r], bw[c], acc[r][c]);
            }
            if (pf) {                     // stage prefetched chunk (covers latency)
                st_chunk2(btb[buf ^ 1], j0, nx0);
                st_chunk2(btb[buf ^ 1], j1, nx1);
            }
            if ((t & 127) == 127) {       // np-composed score + argmin for this jb
                float nrv[2][4];
#pragma unroll
                for (int h = 0; h < 2; ++h)
#pragma unroll
                    for (int c = 0; c < 4; ++c)
                        nrv[h][c] = nr[jb + h * 256 + tx * 4 + c];
#pragma unroll
                for (int r = 0; r < 8; ++r) {
                    float t1 = 3.4e38f; int u1 = 0x7ffffff;
#pragma unroll
                    for (int h = 0; h < 2; ++h)
#pragma unroll
                        for (int c = 0; c < 4; ++c) {
                            int j = jb + h * 256 + tx * 4 + c;
                            float m2 = __fmul_rn(2.f, acc[r][h * 4 + c]);
                            float sc2 = __fadd_rn(__fsub_rn(Srow[r], m2), nrv[h][c]);
                            if (better(sc2, j, t1, u1)) { t1 = sc2; u1 = j; }
                        }
#pragma unroll
                    for (int off = 32; off >= 1; off >>= 1) {
                        float ob = __shfl_xor(t1, off, 64);
                        int   oj = __shfl_xor(u1, off, 64);
                        if (better(ob, oj, t1, u1)) { t1 = ob; u1 = oj; }
                    }
                    if (tx == 0 && better(t1, u1, rb[r], rjx[r])) { rb[r] = t1; rjx[r] = u1; }
                }
            }
        }
        // publish chosen indices: LDS overlay (disjoint from btb[1], which the
        // last chunk read) + direct global write of the index output
        if (tx == 0) {
#pragma unroll
            for (int r = 0; r < 8; ++r) {
                sci[row0 + r] = rjx[r];
                out[2 + (size_t)(base + row0 + r) * KST + s] = (float)rjx[r];
            }
        }
        __syncthreads();                  // (D) rowidx visible

        // residual update + loss (elementwise fp32; banks 2-way via remap)
        {
            int bi = sci[urow];
            const float4* cp = (const float4*)(cb + (size_t)bi * DD + ug * 32);
#pragma unroll
            for (int dq = 0; dq < 8; ++dq) {
                float4 v = cp[dq];
                int d = ug * 32 + dq * 4;
                float e0 = __fsub_rn(a_t[d + 0][urow], v.x); a_t[d + 0][urow] = e0;
                float e1 = __fsub_rn(a_t[d + 1][urow], v.y); a_t[d + 1][urow] = e1;
                float e2 = __fsub_rn(a_t[d + 2][urow], v.z); a_t[d + 2][urow] = e2;
                float e3 = __fsub_rn(a_t[d + 3][urow], v.w); a_t[d + 3][urow] = e3;
                loss_acc += e0 * e0 + e1 * e1 + e2 * e2 + e3 * e3;
            }
        }
    }
    __syncthreads();                      // (E) a_t final; sci reads done

    // ---- outputs ---- (indices already written per stage)
    float* q = out + 2 + (size_t)NROWS * KST;
    for (int i = tid; i < ROWS * DD / 4; i += 256) {
        int row = i >> 6, dq = i & 63, d = dq * 4;
        float4 xv = ((const float4*)(x + (size_t)(base + row) * DD))[dq];
        float4 o;
        o.x = xv.x - a_t[d + 0][row];
        o.y = xv.y - a_t[d + 1][row];
        o.z = xv.z - a_t[d + 2][row];
        o.w = xv.w - a_t[d + 3][row];
        ((float4*)(q + (size_t)(base + row) * DD))[dq] = o;
    }
#pragma unroll
    for (int off = 32; off >= 1; off >>= 1) loss_acc += __shfl_down(loss_acc, off, 64);
    if ((tid & 63) == 0) sc[tid >> 6] = loss_acc;   // wred overlay
    __syncthreads();
    if (tid == 0) {
        float t = sc[0] + sc[1] + sc[2] + sc[3];
        t *= (1.f / ((float)NROWS * (float)DD));
        atomicAdd(out + 0, t);
        atomicAdd(out + 1, t);
    }
}

// ---------------------------------------------------------------------------
extern "C" void kernel_launch(void* const* d_in, const int* in_sizes, int n_in,
                              void* d_out, int out_size, void* d_ws, size_t ws_size,
                              hipStream_t stream) {
    const float* x   = (const float*)d_in[0];   // [16,2048,256] fp32
    const float* cbs = (const float*)d_in[1];   // [8,1024,256] fp32
    float* out = (float*)d_out;
    float* n32 = (float*)d_ws;                  // 8192 floats

    hipMemsetAsync(d_out, 0, 2 * sizeof(float), stream);
    norms_kernel<<<32, 256, 0, stream>>>(cbs, n32);
    rvq_kernel<<<NROWS / ROWS, 256, 0, stream>>>(x, cbs, n32, out);
}

// Round 4
// 3832.302 us; speedup vs baseline: 3.4367x; 1.4720x over previous
//
#include <hip/hip_runtime.h>

// Problem constants (B,S,D=16,2048,256; K codebooks=8, CD=1024)
#define DD    256
#define KST   8
#define CDN   1024
#define NROWS 32768          // B*S
#define ROWS  32             // rows (tokens) per block
#define AST   32             // a_t row stride (bank-perfect for sumsq/update)

// Transposed codebook: cbT[s][c][j][4] = cbs[s][j][c*4 + 0..3]
// (c = k-chunk index 0..63). One float4 per (chunk, codeword): per-chunk B
// loads are lane-consecutive -> perfectly coalesced 1KB wave transactions.
__device__ float cbT_buf[(size_t)KST * 64 * CDN * 4];   // 8 MB static

__device__ __forceinline__ bool better(float a, int ja, float b, int jb_) {
    return (a < b) || (a == b && ja < jb_);
}

// ---------------------------------------------------------------------------
// numpy AVX512 pairwise sum-of-squares over 256 values (bit-emulated).
template <typename F>
__device__ __forceinline__ float np_sumsq_256(F ld) {
    float Sv = 0.f;
#pragma unroll
    for (int blk = 0; blk < 2; ++blk) {
        const int o = blk * 128;
        float w[16];
#pragma unroll
        for (int l = 0; l < 16; ++l) {
            float v[8];
#pragma unroll
            for (int j = 0; j < 8; ++j) {
                float xv = ld(o + 16 * j + l);
                v[j] = __fmul_rn(xv, xv);
            }
            float a01 = __fadd_rn(v[0], v[1]);
            float a23 = __fadd_rn(v[2], v[3]);
            float a45 = __fadd_rn(v[4], v[5]);
            float a67 = __fadd_rn(v[6], v[7]);
            w[l] = __fadd_rn(__fadd_rn(a01, a23), __fadd_rn(a45, a67));
        }
        float t8[8];
#pragma unroll
        for (int l = 0; l < 8; ++l) t8[l] = __fadd_rn(w[l], w[l + 8]);
        float t4[4];
#pragma unroll
        for (int l = 0; l < 4; ++l) t4[l] = __fadd_rn(t8[l], t8[l + 4]);
        float t2_0 = __fadd_rn(t4[0], t4[2]);
        float t2_1 = __fadd_rn(t4[1], t4[3]);
        float bs = __fadd_rn(t2_0, t2_1);
        Sv = (blk == 0) ? bs : __fadd_rn(Sv, bs);
    }
    return Sv;
}

// ---------------------------------------------------------------------------
__global__ __launch_bounds__(256) void norms_kernel(const float* __restrict__ cb,
                                                    float* __restrict__ n32) {
    int j = blockIdx.x * 256 + threadIdx.x;   // 0..8191
    const float* p = cb + (size_t)j * DD;
    n32[j] = np_sumsq_256([&](int i) { return p[i]; });
}

// ---------------------------------------------------------------------------
// One-time codebook transpose into cbT_buf. Coalesced float4 writes
// (consecutive tid -> consecutive 16B); strided reads are a one-time ~10us.
__global__ __launch_bounds__(256) void tr_kernel(const float* __restrict__ cb) {
    int idx = blockIdx.x * 256 + threadIdx.x;  // 0 .. 8*64*1024-1
    int j = idx & 1023;
    int c = (idx >> 10) & 63;
    int s = idx >> 16;
    float4 v = *(const float4*)(cb + ((size_t)(s * CDN + j) * DD) + c * 4);
    *(float4*)(cbT_buf + (size_t)idx * 4) = v;
}

// ---------------------------------------------------------------------------
// Fused RVQ — numpy-fp32 emulation, barrier-free sweep structure.
// Round 1-3 diagnosis: the block-wide double-buffered LDS B-staging costs a
// __syncthreads + vmcnt/lgkmcnt drain per chunk (256-2048 barriers/kernel);
// per-chunk wall was ~3.7x the FMA issue demand (VALUBusy 21-35%).
// Fix: each thread OWNS 2 codewords per half-sweep (registers, no shared B),
// accumulating acc[2][32] against all 32 rows; A comes from wave-uniform LDS
// broadcasts. The whole 256-dim k-loop has ZERO barriers; only 4 barriers
// per stage (rowS, argmin-merge, sci, update). B loads: one float4/chunk/cw
// from the pre-transposed codebook, lane-consecutive -> coalesced, L2-served,
// issued one chunk ahead in registers.
// Exactness: each (row,cw) dot is a single-accumulator FMA chain, k ascending
// 0..255; score composition __fadd(__fsub(Srow, __fmul(2,acc)), norm) and
// lexicographic-min argmin are unchanged -> bit-identical outputs.
__global__ __launch_bounds__(256, 3) void rvq_kernel(const float* __restrict__ x,
                                                     const float* __restrict__ cbs,
                                                     const float* __restrict__ n32,
                                                     float* __restrict__ out) {
    __shared__ __align__(16) float a_t[DD][AST];   // 32768 B residual^T
    __shared__ float rowS[ROWS];                   // np sum(res*res) per row
    __shared__ float redS[2][4][ROWS];             // per-half, per-wave best score
    __shared__ int   redI[2][4][ROWS];             // per-half, per-wave best index
    __shared__ int   sci[ROWS];                    // chosen index per row
    __shared__ float wred[4];

    const int tid  = threadIdx.x;
    const int base = blockIdx.x * ROWS;
    const int tx   = tid & 63;            // lane
    const int ty   = tid >> 6;            // wave id
    const int urow = tid & 31;            // update row
    const int ug   = tid >> 5;            // owned 32-dim segment

    for (int i = tid; i < ROWS * DD / 4; i += 256) {
        int row = i >> 6;
        int dq  = i & 63;
        float4 v = ((const float4*)(x + (size_t)(base + row) * DD))[dq];
        int d = dq * 4;
        a_t[d + 0][row] = v.x; a_t[d + 1][row] = v.y;
        a_t[d + 2][row] = v.z; a_t[d + 3][row] = v.w;
    }

    float loss_acc = 0.f;

    for (int s = 0; s < KST; ++s) {
        const float* cb  = cbs + (size_t)s * CDN * DD;
        const float* nr  = n32 + s * CDN;
        const float* cts = cbT_buf + ((size_t)s << 18);   // s * 64*1024*4
        __syncthreads();                  // (A) a_t stable; prev sci reads done

        // np-AVX512 S = sum(res*res) per row (AST=32: conflict-free)
        if (tid < ROWS) {
            int row = tid;
            rowS[row] = np_sumsq_256([&](int i) { return a_t[i][row]; });
        }
        __syncthreads();                  // (B) rowS visible

        for (int h = 0; h < 2; ++h) {
            const int j0 = h * 512 + tid;
            const int j1 = j0 + 256;
            const float n0 = nr[j0];
            const float n1 = nr[j1];
            const float* q0 = cts + (size_t)j0 * 4;   // cbT[s][0][j0][.]
            const float* q1 = cts + (size_t)j1 * 4;

            float acc0[ROWS], acc1[ROWS];
#pragma unroll
            for (int r = 0; r < ROWS; ++r) { acc0[r] = 0.f; acc1[r] = 0.f; }

            // one chunk = 4 k-values; 64 chunks; barrier-free, reg dbuf
            auto chunk = [&](int kk, float4 b0, float4 b1) {
                float b0a[4] = {b0.x, b0.y, b0.z, b0.w};
                float b1a[4] = {b1.x, b1.y, b1.z, b1.w};
#pragma unroll
                for (int k = 0; k < 4; ++k) {
#pragma unroll
                    for (int rq = 0; rq < 8; ++rq) {
                        // wave-uniform b128 broadcast (conflict-free)
                        float4 a = *(const float4*)&a_t[kk + k][rq * 4];
                        acc0[rq * 4 + 0] = __builtin_fmaf(b0a[k], a.x, acc0[rq * 4 + 0]);
                        acc0[rq * 4 + 1] = __builtin_fmaf(b0a[k], a.y, acc0[rq * 4 + 1]);
                        acc0[rq * 4 + 2] = __builtin_fmaf(b0a[k], a.z, acc0[rq * 4 + 2]);
                        acc0[rq * 4 + 3] = __builtin_fmaf(b0a[k], a.w, acc0[rq * 4 + 3]);
                        acc1[rq * 4 + 0] = __builtin_fmaf(b1a[k], a.x, acc1[rq * 4 + 0]);
                        acc1[rq * 4 + 1] = __builtin_fmaf(b1a[k], a.y, acc1[rq * 4 + 1]);
                        acc1[rq * 4 + 2] = __builtin_fmaf(b1a[k], a.z, acc1[rq * 4 + 2]);
                        acc1[rq * 4 + 3] = __builtin_fmaf(b1a[k], a.w, acc1[rq * 4 + 3]);
                    }
                }
            };

            float4 bc0 = *(const float4*)q0;
            float4 bc1 = *(const float4*)q1;
            for (int kk = 0; kk < DD - 4; kk += 4) {
                const size_t off = (size_t)((kk >> 2) + 1) * 4096;  // next chunk
                float4 bn0 = *(const float4*)(q0 + off);
                float4 bn1 = *(const float4*)(q1 + off);
                chunk(kk, bc0, bc1);
                bc0 = bn0; bc1 = bn1;
            }
            chunk(DD - 4, bc0, bc1);      // last chunk, no prefetch

            // per-row np-composed score + 64-lane argmin butterfly
#pragma unroll
            for (int r = 0; r < ROWS; ++r) {
                float Sr  = rowS[r];      // wave-uniform broadcast
                float m20 = __fmul_rn(2.f, acc0[r]);
                float sc0 = __fadd_rn(__fsub_rn(Sr, m20), n0);
                float m21 = __fmul_rn(2.f, acc1[r]);
                float sc1 = __fadd_rn(__fsub_rn(Sr, m21), n1);
                float t1 = sc0; int u1 = j0;
                if (better(sc1, j1, t1, u1)) { t1 = sc1; u1 = j1; }
#pragma unroll
                for (int off = 32; off >= 1; off >>= 1) {
                    float ob = __shfl_xor(t1, off, 64);
                    int   oj = __shfl_xor(u1, off, 64);
                    if (better(ob, oj, t1, u1)) { t1 = ob; u1 = oj; }
                }
                if (tx == r) { redS[h][ty][r] = t1; redI[h][ty][r] = u1; }
            }
        }
        __syncthreads();                  // (C) redS/redI visible

        // merge 8 candidates per row (2 halves x 4 waves); lexicographic min
        if (tid < ROWS) {
            float tb = redS[0][0][tid]; int tj = redI[0][0][tid];
#pragma unroll
            for (int h2 = 0; h2 < 2; ++h2)
#pragma unroll
                for (int w = 0; w < 4; ++w) {
                    if (h2 == 0 && w == 0) continue;
                    float ob = redS[h2][w][tid]; int oj = redI[h2][w][tid];
                    if (better(ob, oj, tb, tj)) { tb = ob; tj = oj; }
                }
            sci[tid] = tj;
            out[2 + (size_t)(base + tid) * KST + s] = (float)tj;
        }
        __syncthreads();                  // (D) sci visible

        // residual update + loss (elementwise fp32; banks 2-way via remap)
        {
            int bi = sci[urow];
            const float4* cp = (const float4*)(cb + (size_t)bi * DD + ug * 32);
#pragma unroll
            for (int dq = 0; dq < 8; ++dq) {
                float4 v = cp[dq];
                int d = ug * 32 + dq * 4;
                float e0 = __fsub_rn(a_t[d + 0][urow], v.x); a_t[d + 0][urow] = e0;
                float e1 = __fsub_rn(a_t[d + 1][urow], v.y); a_t[d + 1][urow] = e1;
                float e2 = __fsub_rn(a_t[d + 2][urow], v.z); a_t[d + 2][urow] = e2;
                float e3 = __fsub_rn(a_t[d + 3][urow], v.w); a_t[d + 3][urow] = e3;
                loss_acc += e0 * e0 + e1 * e1 + e2 * e2 + e3 * e3;
            }
        }
    }
    __syncthreads();                      // (E) a_t final

    // ---- outputs ---- (indices already written per stage)
    float* q = out + 2 + (size_t)NROWS * KST;
    for (int i = tid; i < ROWS * DD / 4; i += 256) {
        int row = i >> 6, dq = i & 63, d = dq * 4;
        float4 xv = ((const float4*)(x + (size_t)(base + row) * DD))[dq];
        float4 o;
        o.x = xv.x - a_t[d + 0][row];
        o.y = xv.y - a_t[d + 1][row];
        o.z = xv.z - a_t[d + 2][row];
        o.w = xv.w - a_t[d + 3][row];
        ((float4*)(q + (size_t)(base + row) * DD))[dq] = o;
    }
#pragma unroll
    for (int off = 32; off >= 1; off >>= 1) loss_acc += __shfl_down(loss_acc, off, 64);
    if ((tid & 63) == 0) wred[tid >> 6] = loss_acc;
    __syncthreads();
    if (tid == 0) {
        float t = wred[0] + wred[1] + wred[2] + wred[3];
        t *= (1.f / ((float)NROWS * (float)DD));
        atomicAdd(out + 0, t);
        atomicAdd(out + 1, t);
    }
}

// ---------------------------------------------------------------------------
extern "C" void kernel_launch(void* const* d_in, const int* in_sizes, int n_in,
                              void* d_out, int out_size, void* d_ws, size_t ws_size,
                              hipStream_t stream) {
    const float* x   = (const float*)d_in[0];   // [16,2048,256] fp32
    const float* cbs = (const float*)d_in[1];   // [8,1024,256] fp32
    float* out = (float*)d_out;
    float* n32 = (float*)d_ws;                  // 8192 floats

    hipMemsetAsync(d_out, 0, 2 * sizeof(float), stream);
    tr_kernel<<<2048, 256, 0, stream>>>(cbs);
    norms_kernel<<<32, 256, 0, stream>>>(cbs, n32);
    rvq_kernel<<<NROWS / ROWS, 256, 0, stream>>>(x, cbs, n32, out);
}

// Round 5
// 2355.500 us; speedup vs baseline: 5.5914x; 1.6270x over previous
//
#include <hip/hip_runtime.h>

// Problem constants (B,S,D=16,2048,256; K codebooks=8, CD=1024)
#define DD    256
#define KST   8
#define CDN   1024
#define NROWS 32768          // B*S
#define ROWS  32             // rows (tokens) per block
#define AST   32             // a_t row stride (bank-perfect for sumsq/update)

// Transposed codebook, float2-granular:
// cbT[s][c2][j][2] = cb[s][j][2*c2 + 0..1], c2 = 0..127.
// Per-chunk B loads are lane-consecutive 8B -> perfectly coalesced.
__device__ float cbT_buf[(size_t)KST * 128 * CDN * 2];   // 8 MB static

__device__ __forceinline__ bool better(float a, int ja, float b, int jb_) {
    return (a < b) || (a == b && ja < jb_);
}

// ---------------------------------------------------------------------------
// numpy AVX512 pairwise sum-of-squares over 256 values (bit-emulated).
template <typename F>
__device__ __forceinline__ float np_sumsq_256(F ld) {
    float Sv = 0.f;
#pragma unroll
    for (int blk = 0; blk < 2; ++blk) {
        const int o = blk * 128;
        float w[16];
#pragma unroll
        for (int l = 0; l < 16; ++l) {
            float v[8];
#pragma unroll
            for (int j = 0; j < 8; ++j) {
                float xv = ld(o + 16 * j + l);
                v[j] = __fmul_rn(xv, xv);
            }
            float a01 = __fadd_rn(v[0], v[1]);
            float a23 = __fadd_rn(v[2], v[3]);
            float a45 = __fadd_rn(v[4], v[5]);
            float a67 = __fadd_rn(v[6], v[7]);
            w[l] = __fadd_rn(__fadd_rn(a01, a23), __fadd_rn(a45, a67));
        }
        float t8[8];
#pragma unroll
        for (int l = 0; l < 8; ++l) t8[l] = __fadd_rn(w[l], w[l + 8]);
        float t4[4];
#pragma unroll
        for (int l = 0; l < 4; ++l) t4[l] = __fadd_rn(t8[l], t8[l + 4]);
        float t2_0 = __fadd_rn(t4[0], t4[2]);
        float t2_1 = __fadd_rn(t4[1], t4[3]);
        float bs = __fadd_rn(t2_0, t2_1);
        Sv = (blk == 0) ? bs : __fadd_rn(Sv, bs);
    }
    return Sv;
}

// ---------------------------------------------------------------------------
__global__ __launch_bounds__(256) void norms_kernel(const float* __restrict__ cb,
                                                    float* __restrict__ n32) {
    int j = blockIdx.x * 256 + threadIdx.x;   // 0..8191
    const float* p = cb + (size_t)j * DD;
    n32[j] = np_sumsq_256([&](int i) { return p[i]; });
}

// ---------------------------------------------------------------------------
// One-time codebook transpose into cbT_buf (float2 granules).
// idx = s*131072 + c2*1024 + j; writes coalesced 8B.
__global__ __launch_bounds__(256) void tr_kernel(const float* __restrict__ cb) {
    int idx = blockIdx.x * 256 + threadIdx.x;  // 0 .. 1048575
    int j  = idx & 1023;
    int c2 = (idx >> 10) & 127;
    int s  = idx >> 17;
    float2 v = *(const float2*)(cb + ((size_t)(s * CDN + j) * DD) + c2 * 2);
    *(float2*)(cbT_buf + (size_t)idx * 2) = v;
}

// ---------------------------------------------------------------------------
// Fused RVQ — numpy-fp32 emulation, LDS-pipe-balanced orientation.
// Rounds 1-4 all measured VALUBusy 35-39%: the per-CU LDS read pipe was the
// bottleneck (broadcast ds_read_b128 costs ~12cyc like any b128; 32 reads
// per 256 FMAs -> LDS 3:1 over VALU). New orientation: wave ty owns rows
// ty*8..ty*8+7 (A broadcast reads drop to 4 b128 per 128 FMAs -> VALU-bound);
// lane cg owns 8 codewords j = h*512 + slot*64 + cg, B in registers from the
// float2-transposed codebook (coalesced, ping-pong prefetch, zero barriers in
// the k-loop). Waves own disjoint rows -> argmin butterfly needs no
// cross-wave merge. 3 barriers/stage.
// __launch_bounds__(256,2): this toolchain empirically caps VGPR at 256/N
// (N=3 -> 84 = the round-4 spill; N=2 -> 128 which fits the ~124-reg demand
// and keeps the 4-waves/SIMD tier).
// Exactness: each (row,cw) dot is a single-accumulator FMA chain, k ascending
// 0..255; score composition __fadd(__fsub(S, __fmul(2,acc)), norm) and
// lexicographic-min argmin unchanged -> bit-identical outputs.
__global__ __launch_bounds__(256, 2) void rvq_kernel(const float* __restrict__ x,
                                                     const float* __restrict__ cbs,
                                                     const float* __restrict__ n32,
                                                     float* __restrict__ out) {
    __shared__ __align__(16) float a_t[DD][AST];   // 32768 B residual^T
    __shared__ float rowS[ROWS];                   // np sum(res*res) per row
    __shared__ float bestS[ROWS];                  // running best score per row
    __shared__ int   bestI[ROWS];                  // running best index per row
    __shared__ float wred[4];

    const int tid  = threadIdx.x;
    const int base = blockIdx.x * ROWS;
    const int cg   = tid & 63;            // lane: codeword group
    const int ty   = tid >> 6;            // wave id = row-group (8 rows)
    const int row0 = ty * 8;
    const int urow = tid & 31;            // update row
    const int ug   = tid >> 5;            // owned 32-dim segment

    for (int i = tid; i < ROWS * DD / 4; i += 256) {
        int row = i >> 6;
        int dq  = i & 63;
        float4 v = ((const float4*)(x + (size_t)(base + row) * DD))[dq];
        int d = dq * 4;
        a_t[d + 0][row] = v.x; a_t[d + 1][row] = v.y;
        a_t[d + 2][row] = v.z; a_t[d + 3][row] = v.w;
    }

    float loss_acc = 0.f;

    for (int s = 0; s < KST; ++s) {
        const float* cb  = cbs + (size_t)s * CDN * DD;
        const float* nr  = n32 + s * CDN;
        const float* cts = cbT_buf + ((size_t)s << 18);   // s * 128*1024*2
        __syncthreads();                  // (A) a_t stable; prev bestI reads done

        // np-AVX512 S = sum(res*res) per row (AST=32: conflict-free)
        if (tid < ROWS) {
            int row = tid;
            rowS[row] = np_sumsq_256([&](int i) { return a_t[i][row]; });
            bestS[row] = 3.4e38f;
            bestI[row] = 0x7ffffff;
        }
        __syncthreads();                  // (B) rowS/best init visible

        for (int h = 0; h < 2; ++h) {
            float acc[8][8];              // [slot][r]
#pragma unroll
            for (int sl = 0; sl < 8; ++sl)
#pragma unroll
                for (int r = 0; r < 8; ++r) acc[sl][r] = 0.f;

            // B base for this lane: element (c2*1024 + h*512 + slot*64 + cg)
            const float* bp = cts + ((size_t)(h * 512) + cg) * 2;

            // one 2k-chunk: A = 4 broadcast b128, 128 FMAs, k ascending
            auto do_chunk = [&](int c2v, const float2* bb) {
                float4 x0 = *(const float4*)&a_t[2 * c2v][row0];
                float4 x1 = *(const float4*)&a_t[2 * c2v][row0 + 4];
                float4 y0 = *(const float4*)&a_t[2 * c2v + 1][row0];
                float4 y1 = *(const float4*)&a_t[2 * c2v + 1][row0 + 4];
                float xa[8] = {x0.x, x0.y, x0.z, x0.w, x1.x, x1.y, x1.z, x1.w};
                float ya[8] = {y0.x, y0.y, y0.z, y0.w, y1.x, y1.y, y1.z, y1.w};
#pragma unroll
                for (int sl = 0; sl < 8; ++sl)
#pragma unroll
                    for (int r = 0; r < 8; ++r) {
                        float t = __builtin_fmaf(bb[sl].x, xa[r], acc[sl][r]);
                        acc[sl][r] = __builtin_fmaf(bb[sl].y, ya[r], t);
                    }
            };

            float2 bA[8], bB[8];
#pragma unroll
            for (int sl = 0; sl < 8; ++sl)
                bA[sl] = *(const float2*)(bp + sl * 128);
            for (int c2 = 0; c2 < 128; c2 += 2) {
#pragma unroll
                for (int sl = 0; sl < 8; ++sl)     // prefetch chunk c2+1
                    bB[sl] = *(const float2*)(bp + (size_t)(c2 + 1) * 2048 + sl * 128);
                do_chunk(c2, bA);
                if (c2 + 2 < 128) {
#pragma unroll
                    for (int sl = 0; sl < 8; ++sl) // prefetch chunk c2+2
                        bA[sl] = *(const float2*)(bp + (size_t)(c2 + 2) * 2048 + sl * 128);
                }
                do_chunk(c2 + 1, bB);
            }

            // np-composed score + per-row 64-lane argmin butterfly
            float nrv[8];
#pragma unroll
            for (int sl = 0; sl < 8; ++sl) nrv[sl] = nr[h * 512 + sl * 64 + cg];
#pragma unroll
            for (int r = 0; r < 8; ++r) {
                int row = row0 + r;
                float Sr = rowS[row];     // wave-uniform broadcast
                float t1 = 3.4e38f; int u1 = 0x7ffffff;
#pragma unroll
                for (int sl = 0; sl < 8; ++sl) {
                    int j = h * 512 + sl * 64 + cg;
                    float m2 = __fmul_rn(2.f, acc[sl][r]);
                    float sc2 = __fadd_rn(__fsub_rn(Sr, m2), nrv[sl]);
                    if (better(sc2, j, t1, u1)) { t1 = sc2; u1 = j; }
                }
#pragma unroll
                for (int off = 32; off >= 1; off >>= 1) {
                    float ob = __shfl_xor(t1, off, 64);
                    int   oj = __shfl_xor(u1, off, 64);
                    if (better(ob, oj, t1, u1)) { t1 = ob; u1 = oj; }
                }
                if (cg == r) {            // this wave owns the row: no merge
                    if (better(t1, u1, bestS[row], bestI[row])) {
                        bestS[row] = t1; bestI[row] = u1;
                    }
                }
            }
        }
        __syncthreads();                  // (C) bestI final for all rows

        if (tid < ROWS)                   // index output, direct to global
            out[2 + (size_t)(base + tid) * KST + s] = (float)bestI[tid];

        // residual update + loss (elementwise fp32; banks 2-way via remap)
        {
            int bi = bestI[urow];
            const float4* cp = (const float4*)(cb + (size_t)bi * DD + ug * 32);
#pragma unroll
            for (int dq = 0; dq < 8; ++dq) {
                float4 v = cp[dq];
                int d = ug * 32 + dq * 4;
                float e0 = __fsub_rn(a_t[d + 0][urow], v.x); a_t[d + 0][urow] = e0;
                float e1 = __fsub_rn(a_t[d + 1][urow], v.y); a_t[d + 1][urow] = e1;
                float e2 = __fsub_rn(a_t[d + 2][urow], v.z); a_t[d + 2][urow] = e2;
                float e3 = __fsub_rn(a_t[d + 3][urow], v.w); a_t[d + 3][urow] = e3;
                loss_acc += e0 * e0 + e1 * e1 + e2 * e2 + e3 * e3;
            }
        }
    }
    __syncthreads();                      // (E) a_t final

    // ---- outputs ---- (indices already written per stage)
    float* q = out + 2 + (size_t)NROWS * KST;
    for (int i = tid; i < ROWS * DD / 4; i += 256) {
        int row = i >> 6, dq = i & 63, d = dq * 4;
        float4 xv = ((const float4*)(x + (size_t)(base + row) * DD))[dq];
        float4 o;
        o.x = xv.x - a_t[d + 0][row];
        o.y = xv.y - a_t[d + 1][row];
        o.z = xv.z - a_t[d + 2][row];
        o.w = xv.w - a_t[d + 3][row];
        ((float4*)(q + (size_t)(base + row) * DD))[dq] = o;
    }
#pragma unroll
    for (int off = 32; off >= 1; off >>= 1) loss_acc += __shfl_down(loss_acc, off, 64);
    if ((tid & 63) == 0) wred[tid >> 6] = loss_acc;
    __syncthreads();
    if (tid == 0) {
        float t = wred[0] + wred[1] + wred[2] + wred[3];
        t *= (1.f / ((float)NROWS * (float)DD));
        atomicAdd(out + 0, t);
        atomicAdd(out + 1, t);
    }
}

// ---------------------------------------------------------------------------
extern "C" void kernel_launch(void* const* d_in, const int* in_sizes, int n_in,
                              void* d_out, int out_size, void* d_ws, size_t ws_size,
                              hipStream_t stream) {
    const float* x   = (const float*)d_in[0];   // [16,2048,256] fp32
    const float* cbs = (const float*)d_in[1];   // [8,1024,256] fp32
    float* out = (float*)d_out;
    float* n32 = (float*)d_ws;                  // 8192 floats

    hipMemsetAsync(d_out, 0, 2 * sizeof(float), stream);
    tr_kernel<<<4096, 256, 0, stream>>>(cbs);
    norms_kernel<<<32, 256, 0, stream>>>(cbs, n32);
    rvq_kernel<<<NROWS / ROWS, 256, 0, stream>>>(x, cbs, n32, out);
}

// Round 7
// 2133.470 us; speedup vs baseline: 6.1733x; 1.1041x over previous
//
#include <hip/hip_runtime.h>

// Problem constants (B,S,D=16,2048,256; K codebooks=8, CD=1024)
#define DD    256
#define KST   8
#define CDN   1024
#define NROWS 32768          // B*S
#define ROWS  32             // rows (tokens) per block
#define AST   32             // a_t row stride (bank-perfect for sumsq/update)

// Transposed codebook, float2-granular:
// cbT[s][c2][j][2] = cb[s][j][2*c2 + 0..1], c2 = 0..127.
// Per-chunk B loads are lane-consecutive 8B -> perfectly coalesced.
__device__ float cbT_buf[(size_t)KST * 128 * CDN * 2];   // 8 MB static

__device__ __forceinline__ bool better(float a, int ja, float b, int jb_) {
    return (a < b) || (a == b && ja < jb_);
}

// ---------------------------------------------------------------------------
// numpy AVX512 pairwise sum-of-squares over 256 values (bit-emulated).
template <typename F>
__device__ __forceinline__ float np_sumsq_256(F ld) {
    float Sv = 0.f;
#pragma unroll
    for (int blk = 0; blk < 2; ++blk) {
        const int o = blk * 128;
        float w[16];
#pragma unroll
        for (int l = 0; l < 16; ++l) {
            float v[8];
#pragma unroll
            for (int j = 0; j < 8; ++j) {
                float xv = ld(o + 16 * j + l);
                v[j] = __fmul_rn(xv, xv);
            }
            float a01 = __fadd_rn(v[0], v[1]);
            float a23 = __fadd_rn(v[2], v[3]);
            float a45 = __fadd_rn(v[4], v[5]);
            float a67 = __fadd_rn(v[6], v[7]);
            w[l] = __fadd_rn(__fadd_rn(a01, a23), __fadd_rn(a45, a67));
        }
        float t8[8];
#pragma unroll
        for (int l = 0; l < 8; ++l) t8[l] = __fadd_rn(w[l], w[l + 8]);
        float t4[4];
#pragma unroll
        for (int l = 0; l < 4; ++l) t4[l] = __fadd_rn(t8[l], t8[l + 4]);
        float t2_0 = __fadd_rn(t4[0], t4[2]);
        float t2_1 = __fadd_rn(t4[1], t4[3]);
        float bs = __fadd_rn(t2_0, t2_1);
        Sv = (blk == 0) ? bs : __fadd_rn(Sv, bs);
    }
    return Sv;
}

// ---------------------------------------------------------------------------
__global__ __launch_bounds__(256) void norms_kernel(const float* __restrict__ cb,
                                                    float* __restrict__ n32) {
    int j = blockIdx.x * 256 + threadIdx.x;   // 0..8191
    const float* p = cb + (size_t)j * DD;
    n32[j] = np_sumsq_256([&](int i) { return p[i]; });
}

// ---------------------------------------------------------------------------
// One-time codebook transpose into cbT_buf (float2 granules).
// idx = s*131072 + c2*1024 + j; writes coalesced 8B.
__global__ __launch_bounds__(256) void tr_kernel(const float* __restrict__ cb) {
    int idx = blockIdx.x * 256 + threadIdx.x;  // 0 .. 1048575
    int j  = idx & 1023;
    int c2 = (idx >> 10) & 127;
    int s  = idx >> 17;
    float2 v = *(const float2*)(cb + ((size_t)(s * CDN + j) * DD) + c2 * 2);
    *(float2*)(cbT_buf + (size_t)idx * 2) = v;
}

// ---------------------------------------------------------------------------
// Fused RVQ — numpy-fp32 emulation, latency-pipelined orientation.
// Round-5 accounting: FMA issue = 37% of wall, VALUBusy 45% -> ~55% of wall
// was wave stalls, dominated by the per-chunk LDS A-broadcast latency (~120cy
// exposed per 256cy chunk; B was already prefetched, A was not).
// This round: software-pipeline A. Each 2k-chunk splits into x-FMAs (k=2c)
// and y-FMAs (k=2c+1); ya(c) is loaded before the x-phase and xa(c+1) between
// the phases, so every ds_read has >=128 cycles of independent FMAs before
// first use. Per-accumulator chain order is untouched (k ascending, single
// accumulator) -> scores bit-identical.
// Also: sumsq distributed (wave ty's lanes 0-7 compute its own rows; code
// path per row identical -> bit-exact), making rowS/bestS/bestI wave-local
// and deleting one barrier: 2 barriers/stage.
__global__ __launch_bounds__(256, 2) void rvq_kernel(const float* __restrict__ x,
                                                     const float* __restrict__ cbs,
                                                     const float* __restrict__ n32,
                                                     float* __restrict__ out) {
    __shared__ __align__(16) float a_t[DD][AST];   // 32768 B residual^T
    __shared__ float rowS[ROWS];                   // np sum(res*res) per row
    __shared__ float bestS[ROWS];                  // running best score per row
    __shared__ int   bestI[ROWS];                  // running best index per row
    __shared__ float wred[4];

    const int tid  = threadIdx.x;
    const int base = blockIdx.x * ROWS;
    const int cg   = tid & 63;            // lane: codeword group
    const int ty   = tid >> 6;            // wave id = row-group (8 rows)
    const int row0 = ty * 8;
    const int urow = tid & 31;            // update row
    const int ug   = tid >> 5;            // owned 32-dim segment

    for (int i = tid; i < ROWS * DD / 4; i += 256) {
        int row = i >> 6;
        int dq  = i & 63;
        float4 v = ((const float4*)(x + (size_t)(base + row) * DD))[dq];
        int d = dq * 4;
        a_t[d + 0][row] = v.x; a_t[d + 1][row] = v.y;
        a_t[d + 2][row] = v.z; a_t[d + 3][row] = v.w;
    }

    float loss_acc = 0.f;

    for (int s = 0; s < KST; ++s) {
        const float* cb  = cbs + (size_t)s * CDN * DD;
        const float* nr  = n32 + s * CDN;
        const float* cts = cbT_buf + ((size_t)s << 18);   // s * 128*1024*2
        __syncthreads();                  // (A) a_t stable; prev bestI reads done

        // np-AVX512 S = sum(res*res): wave ty's lanes 0-7 do rows row0..row0+7
        // (identical per-row serial code path -> bit-exact; wave-local, so no
        // barrier needed before the sweep).
        if (cg < 8) {
            int row = row0 + cg;
            rowS[row] = np_sumsq_256([&](int i) { return a_t[i][row]; });
            bestS[row] = 3.4e38f;
            bestI[row] = 0x7ffffff;
        }

        for (int h = 0; h < 2; ++h) {
            float acc[8][8];              // [slot][r]
#pragma unroll
            for (int sl = 0; sl < 8; ++sl)
#pragma unroll
                for (int r = 0; r < 8; ++r) acc[sl][r] = 0.f;

            // B base for this lane: element (c2*1024 + h*512 + slot*64 + cg)
            const float* bp = cts + ((size_t)(h * 512) + cg) * 2;

            float2 bA_[8], bB_[8];        // B ping-pong (chunk granularity)
            float  xaR[8], yaR[8];        // pipelined A broadcasts

            auto LOADB = [&](float2* dst, int c) {
                const float* q = bp + (size_t)c * 2048;
#pragma unroll
                for (int sl = 0; sl < 8; ++sl)
                    dst[sl] = *(const float2*)(q + sl * 128);
            };
            auto LOADA = [&](float* dst, int kk) {
                float4 p0 = *(const float4*)&a_t[kk][row0];
                float4 p1 = *(const float4*)&a_t[kk][row0 + 4];
                dst[0] = p0.x; dst[1] = p0.y; dst[2] = p0.z; dst[3] = p0.w;
                dst[4] = p1.x; dst[5] = p1.y; dst[6] = p1.z; dst[7] = p1.w;
            };
            auto FMAX = [&](const float2* b, const float* a) {
#pragma unroll
                for (int sl = 0; sl < 8; ++sl)
#pragma unroll
                    for (int r = 0; r < 8; ++r)
                        acc[sl][r] = __builtin_fmaf(b[sl].x, a[r], acc[sl][r]);
            };
            auto FMAY = [&](const float2* b, const float* a) {
#pragma unroll
                for (int sl = 0; sl < 8; ++sl)
#pragma unroll
                    for (int r = 0; r < 8; ++r)
                        acc[sl][r] = __builtin_fmaf(b[sl].y, a[r], acc[sl][r]);
            };

            LOADB(bA_, 0);
            LOADA(xaR, 0);
#pragma unroll 1
            for (int c2 = 0; c2 < 128; c2 += 2) {
                LOADA(yaR, 2 * c2 + 1);   // ya(c2): used after 64 x-FMAs
                LOADB(bB_, c2 + 1);       // B(c2+1): used next chunk
                FMAX(bA_, xaR);           // k = 2*c2
                LOADA(xaR, 2 * c2 + 2);   // xa(c2+1): used after 64 y-FMAs
                FMAY(bA_, yaR);           // k = 2*c2+1
                LOADA(yaR, 2 * c2 + 3);   // ya(c2+1)
                {
                    int cn = (c2 + 2 < 128) ? (c2 + 2) : 127;   // branchless guard
                    LOADB(bA_, cn);       // B(c2+2)
                }
                FMAX(bB_, xaR);           // k = 2*c2+2
                {
                    int kn = (2 * c2 + 4 < 256) ? (2 * c2 + 4) : 254;
                    LOADA(xaR, kn);       // xa(c2+2)
                }
                FMAY(bB_, yaR);           // k = 2*c2+3
            }

            // np-composed score + per-row 64-lane argmin butterfly
            float nrv[8];
#pragma unroll
            for (int sl = 0; sl < 8; ++sl) nrv[sl] = nr[h * 512 + sl * 64 + cg];
#pragma unroll
            for (int r = 0; r < 8; ++r) {
                int row = row0 + r;
                float Sr = rowS[row];     // wave-local (written by own lanes 0-7)
                float t1 = 3.4e38f; int u1 = 0x7ffffff;
#pragma unroll
                for (int sl = 0; sl < 8; ++sl) {
                    int j = h * 512 + sl * 64 + cg;
                    float m2 = __fmul_rn(2.f, acc[sl][r]);
                    float sc2 = __fadd_rn(__fsub_rn(Sr, m2), nrv[sl]);
                    if (better(sc2, j, t1, u1)) { t1 = sc2; u1 = j; }
                }
#pragma unroll
                for (int off = 32; off >= 1; off >>= 1) {
                    float ob = __shfl_xor(t1, off, 64);
                    int   oj = __shfl_xor(u1, off, 64);
                    if (better(ob, oj, t1, u1)) { t1 = ob; u1 = oj; }
                }
                if (cg == r) {            // this wave owns the row: no merge
                    if (better(t1, u1, bestS[row], bestI[row])) {
                        bestS[row] = t1; bestI[row] = u1;
                    }
                }
            }
        }

        if (cg < 8) {                     // index output, wave-local rows
            int row = row0 + cg;
            out[2 + (size_t)(base + row) * KST + s] = (float)bestI[row];
        }
        __syncthreads();                  // (C) bestI final for all rows

        // residual update + loss (elementwise fp32; banks 2-way via remap)
        {
            int bi = bestI[urow];
            const float4* cp = (const float4*)(cb + (size_t)bi * DD + ug * 32);
#pragma unroll
            for (int dq = 0; dq < 8; ++dq) {
                float4 v = cp[dq];
                int d = ug * 32 + dq * 4;
                float e0 = __fsub_rn(a_t[d + 0][urow], v.x); a_t[d + 0][urow] = e0;
                float e1 = __fsub_rn(a_t[d + 1][urow], v.y); a_t[d + 1][urow] = e1;
                float e2 = __fsub_rn(a_t[d + 2][urow], v.z); a_t[d + 2][urow] = e2;
                float e3 = __fsub_rn(a_t[d + 3][urow], v.w); a_t[d + 3][urow] = e3;
                loss_acc += e0 * e0 + e1 * e1 + e2 * e2 + e3 * e3;
            }
        }
    }
    __syncthreads();                      // (E) a_t final

    // ---- outputs ---- (indices already written per stage)
    float* q = out + 2 + (size_t)NROWS * KST;
    for (int i = tid; i < ROWS * DD / 4; i += 256) {
        int row = i >> 6, dq = i & 63, d = dq * 4;
        float4 xv = ((const float4*)(x + (size_t)(base + row) * DD))[dq];
        float4 o;
        o.x = xv.x - a_t[d + 0][row];
        o.y = xv.y - a_t[d + 1][row];
        o.z = xv.z - a_t[d + 2][row];
        o.w = xv.w - a_t[d + 3][row];
        ((float4*)(q + (size_t)(base + row) * DD))[dq] = o;
    }
#pragma unroll
    for (int off = 32; off >= 1; off >>= 1) loss_acc += __shfl_down(loss_acc, off, 64);
    if ((tid & 63) == 0) wred[tid >> 6] = loss_acc;
    __syncthreads();
    if (tid == 0) {
        float t = wred[0] + wred[1] + wred[2] + wred[3];
        t *= (1.f / ((float)NROWS * (float)DD));
        atomicAdd(out + 0, t);
        atomicAdd(out + 1, t);
    }
}

// ---------------------------------------------------------------------------
extern "C" void kernel_launch(void* const* d_in, const int* in_sizes, int n_in,
                              void* d_out, int out_size, void* d_ws, size_t ws_size,
                              hipStream_t stream) {
    const float* x   = (const float*)d_in[0];   // [16,2048,256] fp32
    const float* cbs = (const float*)d_in[1];   // [8,1024,256] fp32
    float* out = (float*)d_out;
    float* n32 = (float*)d_ws;                  // 8192 floats

    hipMemsetAsync(d_out, 0, 2 * sizeof(float), stream);
    tr_kernel<<<4096, 256, 0, stream>>>(cbs);
    norms_kernel<<<32, 256, 0, stream>>>(cbs, n32);
    rvq_kernel<<<NROWS / ROWS, 256, 0, stream>>>(x, cbs, n32, out);
}